// Round 1
// baseline (779.317 us; speedup 1.0000x reference)
//
#include <hip/hip_runtime.h>
#include <cmath>
#include <cstdint>

#define NLEVELS 16
#define TABLE_SZ (1u << 19)

struct LevelParams {
    uint32_t res[NLEVELS];
    uint32_t size[NLEVELS];
    uint64_t magic[NLEVELS];
};

__global__ __launch_bounds__(256) void hashgrid_kernel(
    const float* __restrict__ x,
    const float* __restrict__ tables,
    float* __restrict__ out,
    int n_points,
    LevelParams lp)
{
    int gid = blockIdx.x * blockDim.x + threadIdx.x;
    int n = gid >> 4;        // point index
    int l = gid & 15;        // level index
    if (n >= n_points) return;

    float x0 = x[(size_t)n * 3 + 0];
    float x1 = x[(size_t)n * 3 + 1];
    float x2 = x[(size_t)n * 3 + 2];

    uint32_t res   = lp.res[l];
    uint32_t size  = lp.size[l];
    uint64_t magic = lp.magic[l];

    float fres = (float)res;
    float xr0 = x0 * fres, xr1 = x1 * fres, xr2 = x2 * fres;
    int ci0 = (int)xr0, ci1 = (int)xr1, ci2 = (int)xr2;
    float cf0 = xr0 - (float)ci0;
    float cf1 = xr1 - (float)ci1;
    float cf2 = xr2 - (float)ci2;

    // per-dim hash contributions for lower (a) and upper (b) corners
    uint32_t h0a = (uint32_t)ci0;               uint32_t h0b = h0a + 1u;
    uint32_t h1a = (uint32_t)ci1 * 2654435761u; uint32_t h1b = h1a + 2654435761u;
    uint32_t h2a = (uint32_t)ci2 * 805459861u;  uint32_t h2b = h2a + 805459861u;

    float w0a = 1.0f - cf0, w1a = 1.0f - cf1, w2a = 1.0f - cf2;

    const float2* __restrict__ t =
        reinterpret_cast<const float2*>(tables) + (size_t)l * TABLE_SZ;

    float s0 = 0.0f, s1 = 0.0f;
#pragma unroll
    for (int k = 0; k < 8; ++k) {
        uint32_t h = ((k & 1) ? h0b : h0a)
                   ^ ((k & 2) ? h1b : h1a)
                   ^ ((k & 4) ? h2b : h2a);
        // h % size via exact magic division: q = floor(h/size)
        uint32_t q = (uint32_t)__umul64hi((uint64_t)h, magic);
        h -= q * size;
        float w = ((k & 1) ? cf0 : w0a)
                * ((k & 2) ? cf1 : w1a)
                * ((k & 4) ? cf2 : w2a);
        float2 f = t[h];
        s0 = fmaf(f.x, w, s0);
        s1 = fmaf(f.y, w, s1);
    }

    reinterpret_cast<float2*>(out)[(size_t)n * NLEVELS + l] = make_float2(s0, s1);
}

extern "C" void kernel_launch(void* const* d_in, const int* in_sizes, int n_in,
                              void* d_out, int out_size, void* d_ws, size_t ws_size,
                              hipStream_t stream) {
    const float* x      = (const float*)d_in[0];
    const float* tables = (const float*)d_in[1];
    float* out          = (float*)d_out;
    int n_points = in_sizes[0] / 3;

    // Replicate the reference's Python double math EXACTLY (same libm calls):
    // _B = exp((log(512)-log(16))/15); res_i = floor(16 * _B**i)
    LevelParams lp;
    double b = exp((log(512.0) - log(16.0)) / 15.0);
    for (int i = 0; i < NLEVELS; ++i) {
        double r = floor(16.0 * pow(b, (double)i));
        uint32_t res = (uint32_t)r;
        uint64_t cube = (uint64_t)res * res * res;
        uint32_t size = (cube < (uint64_t)TABLE_SZ) ? (uint32_t)cube : TABLE_SZ;
        lp.res[i]   = res;
        lp.size[i]  = size;
        // magic = floor(2^64/size)+1 ; exact floor-div for all n < 2^32
        lp.magic[i] = ~0ULL / size + 1ULL;
    }

    int total = n_points * NLEVELS;
    int block = 256;
    int grid = (total + block - 1) / block;
    hashgrid_kernel<<<grid, block, 0, stream>>>(x, tables, out, n_points, lp);
}

// Round 2
// 497.746 us; speedup vs baseline: 1.5657x; 1.5657x over previous
//
#include <hip/hip_runtime.h>
#include <cmath>
#include <cstdint>

#define NLEVELS 16
#define TABLE_SZ (1u << 19)
#define NXCD 8

typedef float f4v __attribute__((ext_vector_type(4)));

struct Params {
    uint32_t res[NLEVELS];
    uint32_t size[NLEVELS];
    uint64_t magic[NLEVELS];
    int lv0[NXCD];   // first level handled by XCD slot s
    int lv1[NXCD];   // second level handled by XCD slot s
};

__device__ __forceinline__ float bf_lo(uint32_t v) { return __uint_as_float(v << 16); }
__device__ __forceinline__ float bf_hi(uint32_t v) { return __uint_as_float(v & 0xFFFF0000u); }

// ---- Kernel 1: fp32 tables -> bf16x2 tables in ws, slot-affine so lines land
// in the XCD L2 that will gather them.
__global__ __launch_bounds__(256) void convert_kernel(
    const float* __restrict__ tab, uint32_t* __restrict__ btab, Params p)
{
    int slot = blockIdx.x & (NXCD - 1);
    uint32_t cb = blockIdx.x >> 3;
    int l0 = p.lv0[slot], l1 = p.lv1[slot];
    uint32_t n0 = p.size[l0], n1 = p.size[l1];
    uint32_t total = n0 + n1;
    uint32_t stride = (gridDim.x >> 3) * 256;
    for (uint32_t i = cb * 256 + threadIdx.x; i < total; i += stride) {
        int l; uint32_t e;
        if (i < n0) { l = l0; e = i; } else { l = l1; e = i - n0; }
        unsigned long long u = __builtin_nontemporal_load(
            (const unsigned long long*)(tab + ((size_t)l * TABLE_SZ + e) * 2));
        uint32_t bx = (uint32_t)u, by = (uint32_t)(u >> 32);
        bx = (bx + 0x7fffu + ((bx >> 16) & 1u)) >> 16;   // RNE fp32->bf16
        by = (by + 0x7fffu + ((by >> 16) & 1u)) >> 16;
        btab[(size_t)l * TABLE_SZ + e] = bx | (by << 16);
    }
}

// ---- Kernel 2: gather + trilerp, level-pure blocks, XCD-affine (blockIdx%8).
// Writes level-major ws[l][rel] (float2) with NT stores.
__global__ __launch_bounds__(256) void gather_kernel(
    const float* __restrict__ x, const uint32_t* __restrict__ btab,
    float2* __restrict__ ws, int p_lo, int passN, Params p)
{
    int slot = blockIdx.x & (NXCD - 1);
    int chunk = blockIdx.x >> 3;
    int rel = chunk * 256 + threadIdx.x;
    int pt = p_lo + rel;

    float x0 = __builtin_nontemporal_load(&x[(size_t)pt * 3 + 0]);
    float x1 = __builtin_nontemporal_load(&x[(size_t)pt * 3 + 1]);
    float x2 = __builtin_nontemporal_load(&x[(size_t)pt * 3 + 2]);

#pragma unroll
    for (int t = 0; t < 2; ++t) {
        int l = t ? p.lv1[slot] : p.lv0[slot];
        uint32_t size  = p.size[l];
        uint64_t magic = p.magic[l];
        float fres = (float)p.res[l];

        float xr0 = x0 * fres, xr1 = x1 * fres, xr2 = x2 * fres;
        int ci0 = (int)xr0, ci1 = (int)xr1, ci2 = (int)xr2;
        float cf0 = xr0 - (float)ci0;
        float cf1 = xr1 - (float)ci1;
        float cf2 = xr2 - (float)ci2;

        uint32_t h0a = (uint32_t)ci0;               uint32_t h0b = h0a + 1u;
        uint32_t h1a = (uint32_t)ci1 * 2654435761u; uint32_t h1b = h1a + 2654435761u;
        uint32_t h2a = (uint32_t)ci2 * 805459861u;  uint32_t h2b = h2a + 805459861u;
        float w0a = 1.0f - cf0, w1a = 1.0f - cf1, w2a = 1.0f - cf2;

        const uint32_t* __restrict__ tl = btab + (size_t)l * TABLE_SZ;
        float s0 = 0.0f, s1 = 0.0f;
#pragma unroll
        for (int k = 0; k < 8; ++k) {
            uint32_t h = ((k & 1) ? h0b : h0a)
                       ^ ((k & 2) ? h1b : h1a)
                       ^ ((k & 4) ? h2b : h2a);
            uint32_t q = (uint32_t)__umul64hi((uint64_t)h, magic);
            h -= q * size;
            float w = ((k & 1) ? cf0 : w0a)
                    * ((k & 2) ? cf1 : w1a)
                    * ((k & 4) ? cf2 : w2a);
            uint32_t v = tl[h];                 // cached gather (L2-resident)
            s0 = fmaf(bf_lo(v), w, s0);
            s1 = fmaf(bf_hi(v), w, s1);
        }
        unsigned long long o = (unsigned long long)__float_as_uint(s0)
                             | ((unsigned long long)__float_as_uint(s1) << 32);
        __builtin_nontemporal_store(o,
            (unsigned long long*)(ws + (size_t)l * passN + rel));
    }
}

// ---- Kernel 3: transpose ws[l][rel] -> out[point][level] via LDS.
__global__ __launch_bounds__(256) void transpose_kernel(
    const float2* __restrict__ ws, f4v* __restrict__ out4, int p_lo, int passN)
{
    __shared__ float2 lds[256 * 17];
    int base = blockIdx.x * 256;
    int tid = threadIdx.x;
#pragma unroll
    for (int l = 0; l < NLEVELS; ++l) {
        unsigned long long u = __builtin_nontemporal_load(
            (const unsigned long long*)(ws + (size_t)l * passN + base + tid));
        float2 v;
        v.x = __uint_as_float((uint32_t)u);
        v.y = __uint_as_float((uint32_t)(u >> 32));
        lds[tid * 17 + l] = v;
    }
    __syncthreads();
    size_t ob = ((size_t)(p_lo + base)) * 8;
#pragma unroll
    for (int k = 0; k < 8; ++k) {
        int flat = k * 256 + tid;
        int ptl = flat >> 3, quad = flat & 7;
        float2 a = lds[ptl * 17 + quad * 2];
        float2 b = lds[ptl * 17 + quad * 2 + 1];
        f4v o = { a.x, a.y, b.x, b.y };
        __builtin_nontemporal_store(o, out4 + ob + flat);
    }
}

// ---- Fallback: round-1 direct kernel (used only if ws too small).
__global__ __launch_bounds__(256) void hashgrid_fallback(
    const float* __restrict__ x, const float* __restrict__ tables,
    float* __restrict__ out, int n_points, Params lp)
{
    int gid = blockIdx.x * blockDim.x + threadIdx.x;
    int n = gid >> 4;
    int l = gid & 15;
    if (n >= n_points) return;
    float x0 = x[(size_t)n * 3 + 0];
    float x1 = x[(size_t)n * 3 + 1];
    float x2 = x[(size_t)n * 3 + 2];
    uint32_t size = lp.size[l];
    uint64_t magic = lp.magic[l];
    float fres = (float)lp.res[l];
    float xr0 = x0 * fres, xr1 = x1 * fres, xr2 = x2 * fres;
    int ci0 = (int)xr0, ci1 = (int)xr1, ci2 = (int)xr2;
    float cf0 = xr0 - (float)ci0, cf1 = xr1 - (float)ci1, cf2 = xr2 - (float)ci2;
    uint32_t h0a = (uint32_t)ci0;               uint32_t h0b = h0a + 1u;
    uint32_t h1a = (uint32_t)ci1 * 2654435761u; uint32_t h1b = h1a + 2654435761u;
    uint32_t h2a = (uint32_t)ci2 * 805459861u;  uint32_t h2b = h2a + 805459861u;
    float w0a = 1.0f - cf0, w1a = 1.0f - cf1, w2a = 1.0f - cf2;
    const float2* t = reinterpret_cast<const float2*>(tables) + (size_t)l * TABLE_SZ;
    float s0 = 0.0f, s1 = 0.0f;
#pragma unroll
    for (int k = 0; k < 8; ++k) {
        uint32_t h = ((k & 1) ? h0b : h0a) ^ ((k & 2) ? h1b : h1a) ^ ((k & 4) ? h2b : h2a);
        uint32_t q = (uint32_t)__umul64hi((uint64_t)h, magic);
        h -= q * size;
        float w = ((k & 1) ? cf0 : w0a) * ((k & 2) ? cf1 : w1a) * ((k & 4) ? cf2 : w2a);
        float2 f = t[h];
        s0 = fmaf(f.x, w, s0);
        s1 = fmaf(f.y, w, s1);
    }
    reinterpret_cast<float2*>(out)[(size_t)n * NLEVELS + l] = make_float2(s0, s1);
}

extern "C" void kernel_launch(void* const* d_in, const int* in_sizes, int n_in,
                              void* d_out, int out_size, void* d_ws, size_t ws_size,
                              hipStream_t stream) {
    const float* x      = (const float*)d_in[0];
    const float* tables = (const float*)d_in[1];
    float* out          = (float*)d_out;
    int n_points = in_sizes[0] / 3;

    // Exact replication of the reference's double-precision level math.
    Params p;
    double b = exp((log(512.0) - log(16.0)) / 15.0);
    for (int i = 0; i < NLEVELS; ++i) {
        double r = floor(16.0 * pow(b, (double)i));
        uint32_t res = (uint32_t)r;
        uint64_t cube = (uint64_t)res * res * res;
        uint32_t size = (cube < (uint64_t)TABLE_SZ) ? (uint32_t)cube : TABLE_SZ;
        p.res[i] = res;
        p.size[i] = size;
        p.magic[i] = ~0ULL / size + 1ULL;   // exact floor-div magic for n < 2^32
    }
    // Byte-balanced level pairs per XCD slot: (7,0)(8,1)...(13,6)(14,15)
    for (int s = 0; s < NXCD - 1; ++s) { p.lv0[s] = 7 + s; p.lv1[s] = s; }
    p.lv0[7] = 14; p.lv1[7] = 15;

    const size_t TAB_BYTES = (size_t)NLEVELS * TABLE_SZ * 4;   // 32 MB bf16 tables
    size_t rem = (ws_size > TAB_BYTES) ? ws_size - TAB_BYTES : 0;
    int passN = (int)((rem / (NLEVELS * sizeof(float2))) & ~(size_t)255);
    if (passN > n_points) passN = n_points;

    if (passN < 256 || (n_points & 255) != 0) {
        // ws too small: direct fp32 path (round-1 kernel).
        int total = n_points * NLEVELS;
        hashgrid_fallback<<<(total + 255) / 256, 256, 0, stream>>>(x, tables, out, n_points, p);
        return;
    }

    uint32_t* btab = (uint32_t*)d_ws;
    float2* wsbuf = (float2*)((char*)d_ws + TAB_BYTES);

    convert_kernel<<<128 * NXCD, 256, 0, stream>>>(tables, btab, p);

    for (int p_lo = 0; p_lo < n_points; p_lo += passN) {
        int cnt = n_points - p_lo;
        if (cnt > passN) cnt = passN;
        int chunks = cnt / 256;
        gather_kernel<<<chunks * NXCD, 256, 0, stream>>>(x, btab, wsbuf, p_lo, cnt, p);
        transpose_kernel<<<chunks, 256, 0, stream>>>(wsbuf, (f4v*)out, p_lo, cnt);
    }
}

// Round 3
// 423.001 us; speedup vs baseline: 1.8424x; 1.1767x over previous
//
#include <hip/hip_runtime.h>
#include <cmath>
#include <cstdint>

#define NLEVELS 16
#define TABLE_SZ (1u << 19)
#define NXCD 8

typedef float f4v __attribute__((ext_vector_type(4)));
typedef uint32_t u32x4 __attribute__((ext_vector_type(4)));

struct Params {
    uint32_t res[NLEVELS];
    uint32_t size[NLEVELS];
    uint64_t magic[NLEVELS];
    int lv0[NXCD];   // first level handled by XCD slot s
    int lv1[NXCD];   // second level handled by XCD slot s
};

__device__ __forceinline__ float bf_lo(uint32_t v) { return __uint_as_float(v << 16); }
__device__ __forceinline__ float bf_hi(uint32_t v) { return __uint_as_float(v & 0xFFFF0000u); }

__device__ __forceinline__ uint32_t pick4(u32x4 f, uint32_t j) {
    uint32_t e01 = (j & 1) ? f[1] : f[0];
    uint32_t e23 = (j & 1) ? f[3] : f[2];
    return (j & 2) ? e23 : e01;
}

// ---- Kernel 1: fp32 tables -> bf16x2 tables in ws, slot-affine so lines land
// in the XCD L2 that will gather them.
__global__ __launch_bounds__(256) void convert_kernel(
    const float* __restrict__ tab, uint32_t* __restrict__ btab, Params p)
{
    int slot = blockIdx.x & (NXCD - 1);
    uint32_t cb = blockIdx.x >> 3;
    int l0 = p.lv0[slot], l1 = p.lv1[slot];
    uint32_t n0 = p.size[l0], n1 = p.size[l1];
    uint32_t total = n0 + n1;
    uint32_t stride = (gridDim.x >> 3) * 256;
    for (uint32_t i = cb * 256 + threadIdx.x; i < total; i += stride) {
        int l; uint32_t e;
        if (i < n0) { l = l0; e = i; } else { l = l1; e = i - n0; }
        unsigned long long u = __builtin_nontemporal_load(
            (const unsigned long long*)(tab + ((size_t)l * TABLE_SZ + e) * 2));
        uint32_t bx = (uint32_t)u, by = (uint32_t)(u >> 32);
        bx = (bx + 0x7fffu + ((bx >> 16) & 1u)) >> 16;   // RNE fp32->bf16
        by = (by + 0x7fffu + ((by >> 16) & 1u)) >> 16;
        btab[(size_t)l * TABLE_SZ + e] = bx | (by << 16);
    }
}

// ---- Kernel 2: gather + trilerp, level-pure blocks, XCD-affine (blockIdx%8).
// x-corner PAIRS fetched with one aligned dwordx4 where possible (~87%),
// halving L2 gather requests. Writes level-major ws[l][rel] with NT stores.
__global__ __launch_bounds__(256) void gather_kernel(
    const float* __restrict__ x, const uint32_t* __restrict__ btab,
    float2* __restrict__ ws, int p_lo, int passN, Params p)
{
    int slot = blockIdx.x & (NXCD - 1);
    int chunk = blockIdx.x >> 3;
    int rel = chunk * 256 + threadIdx.x;
    int pt = p_lo + rel;

    float x0 = __builtin_nontemporal_load(&x[(size_t)pt * 3 + 0]);
    float x1 = __builtin_nontemporal_load(&x[(size_t)pt * 3 + 1]);
    float x2 = __builtin_nontemporal_load(&x[(size_t)pt * 3 + 2]);

#pragma unroll
    for (int t = 0; t < 2; ++t) {
        int l = t ? p.lv1[slot] : p.lv0[slot];
        uint32_t size  = p.size[l];
        uint64_t magic = p.magic[l];
        float fres = (float)p.res[l];

        float xr0 = x0 * fres, xr1 = x1 * fres, xr2 = x2 * fres;
        int ci0 = (int)xr0, ci1 = (int)xr1, ci2 = (int)xr2;
        float cf0 = xr0 - (float)ci0;
        float cf1 = xr1 - (float)ci1;
        float cf2 = xr2 - (float)ci2;

        uint32_t c0u = (uint32_t)ci0, c0v = c0u + 1u;
        uint32_t h1a = (uint32_t)ci1 * 2654435761u; uint32_t h1b = h1a + 2654435761u;
        uint32_t h2a = (uint32_t)ci2 * 805459861u;  uint32_t h2b = h2a + 805459861u;
        float w0a = 1.0f - cf0, w1a = 1.0f - cf1, w2a = 1.0f - cf2;

        const uint32_t* __restrict__ tl = btab + (size_t)l * TABLE_SZ;
        float s0 = 0.0f, s1 = 0.0f;
#pragma unroll
        for (int pq = 0; pq < 4; ++pq) {   // (y,z) combo; corners 2pq, 2pq+1
            uint32_t tyz = ((pq & 1) ? h1b : h1a) ^ ((pq & 2) ? h2b : h2a);
            float wyz = ((pq & 1) ? cf1 : w1a) * ((pq & 2) ? cf2 : w2a);
            uint32_t hU = tyz ^ c0u;
            uint32_t hV = tyz ^ c0v;
            uint32_t rU = hU - (uint32_t)__umul64hi((uint64_t)hU, magic) * size;
            uint32_t rV = hV - (uint32_t)__umul64hi((uint64_t)hV, magic) * size;
            uint32_t base = rU & ~3u;
            u32x4 f = *reinterpret_cast<const u32x4*>(tl + base);
            uint32_t eU = pick4(f, rU & 3u);
            uint32_t eV;
            if ((rV & ~3u) == base) {
                eV = pick4(f, rV & 3u);
            } else {
                eV = tl[rV];               // rare straddle fallback (~13% lanes)
            }
            float wU = w0a * wyz, wV = cf0 * wyz;
            s0 = fmaf(bf_lo(eU), wU, s0);
            s1 = fmaf(bf_hi(eU), wU, s1);
            s0 = fmaf(bf_lo(eV), wV, s0);
            s1 = fmaf(bf_hi(eV), wV, s1);
        }
        unsigned long long o = (unsigned long long)__float_as_uint(s0)
                             | ((unsigned long long)__float_as_uint(s1) << 32);
        __builtin_nontemporal_store(o,
            (unsigned long long*)(ws + (size_t)l * passN + rel));
    }
}

// ---- Kernel 3: transpose ws[l][rel] -> out[point][level] via LDS.
__global__ __launch_bounds__(256) void transpose_kernel(
    const float2* __restrict__ ws, f4v* __restrict__ out4, int p_lo, int passN)
{
    __shared__ float2 lds[256 * 17];
    int base = blockIdx.x * 256;
    int tid = threadIdx.x;
#pragma unroll
    for (int l = 0; l < NLEVELS; ++l) {
        unsigned long long u = __builtin_nontemporal_load(
            (const unsigned long long*)(ws + (size_t)l * passN + base + tid));
        float2 v;
        v.x = __uint_as_float((uint32_t)u);
        v.y = __uint_as_float((uint32_t)(u >> 32));
        lds[tid * 17 + l] = v;
    }
    __syncthreads();
    size_t ob = ((size_t)(p_lo + base)) * 8;
#pragma unroll
    for (int k = 0; k < 8; ++k) {
        int flat = k * 256 + tid;
        int ptl = flat >> 3, quad = flat & 7;
        float2 a = lds[ptl * 17 + quad * 2];
        float2 b = lds[ptl * 17 + quad * 2 + 1];
        f4v o = { a.x, a.y, b.x, b.y };
        __builtin_nontemporal_store(o, out4 + ob + flat);
    }
}

// ---- Fallback: direct fp32 kernel (used only if ws too small).
__global__ __launch_bounds__(256) void hashgrid_fallback(
    const float* __restrict__ x, const float* __restrict__ tables,
    float* __restrict__ out, int n_points, Params lp)
{
    int gid = blockIdx.x * blockDim.x + threadIdx.x;
    int n = gid >> 4;
    int l = gid & 15;
    if (n >= n_points) return;
    float x0 = x[(size_t)n * 3 + 0];
    float x1 = x[(size_t)n * 3 + 1];
    float x2 = x[(size_t)n * 3 + 2];
    uint32_t size = lp.size[l];
    uint64_t magic = lp.magic[l];
    float fres = (float)lp.res[l];
    float xr0 = x0 * fres, xr1 = x1 * fres, xr2 = x2 * fres;
    int ci0 = (int)xr0, ci1 = (int)xr1, ci2 = (int)xr2;
    float cf0 = xr0 - (float)ci0, cf1 = xr1 - (float)ci1, cf2 = xr2 - (float)ci2;
    uint32_t h0a = (uint32_t)ci0;               uint32_t h0b = h0a + 1u;
    uint32_t h1a = (uint32_t)ci1 * 2654435761u; uint32_t h1b = h1a + 2654435761u;
    uint32_t h2a = (uint32_t)ci2 * 805459861u;  uint32_t h2b = h2a + 805459861u;
    float w0a = 1.0f - cf0, w1a = 1.0f - cf1, w2a = 1.0f - cf2;
    const float2* t = reinterpret_cast<const float2*>(tables) + (size_t)l * TABLE_SZ;
    float s0 = 0.0f, s1 = 0.0f;
#pragma unroll
    for (int k = 0; k < 8; ++k) {
        uint32_t h = ((k & 1) ? h0b : h0a) ^ ((k & 2) ? h1b : h1a) ^ ((k & 4) ? h2b : h2a);
        uint32_t q = (uint32_t)__umul64hi((uint64_t)h, magic);
        h -= q * size;
        float w = ((k & 1) ? cf0 : w0a) * ((k & 2) ? cf1 : w1a) * ((k & 4) ? cf2 : w2a);
        float2 f = t[h];
        s0 = fmaf(f.x, w, s0);
        s1 = fmaf(f.y, w, s1);
    }
    reinterpret_cast<float2*>(out)[(size_t)n * NLEVELS + l] = make_float2(s0, s1);
}

extern "C" void kernel_launch(void* const* d_in, const int* in_sizes, int n_in,
                              void* d_out, int out_size, void* d_ws, size_t ws_size,
                              hipStream_t stream) {
    const float* x      = (const float*)d_in[0];
    const float* tables = (const float*)d_in[1];
    float* out          = (float*)d_out;
    int n_points = in_sizes[0] / 3;

    // Exact replication of the reference's double-precision level math.
    Params p;
    double b = exp((log(512.0) - log(16.0)) / 15.0);
    for (int i = 0; i < NLEVELS; ++i) {
        double r = floor(16.0 * pow(b, (double)i));
        uint32_t res = (uint32_t)r;
        uint64_t cube = (uint64_t)res * res * res;
        uint32_t size = (cube < (uint64_t)TABLE_SZ) ? (uint32_t)cube : TABLE_SZ;
        p.res[i] = res;
        p.size[i] = size;
        p.magic[i] = ~0ULL / size + 1ULL;   // exact floor-div magic for n < 2^32
    }
    // Byte-balanced level pairs per XCD slot: (7,0)(8,1)...(13,6)(14,15)
    for (int s = 0; s < NXCD - 1; ++s) { p.lv0[s] = 7 + s; p.lv1[s] = s; }
    p.lv0[7] = 14; p.lv1[7] = 15;

    const size_t TAB_BYTES = (size_t)NLEVELS * TABLE_SZ * 4;   // 32 MB bf16 tables
    size_t rem = (ws_size > TAB_BYTES) ? ws_size - TAB_BYTES : 0;
    int passN = (int)((rem / (NLEVELS * sizeof(float2))) & ~(size_t)255);
    if (passN > n_points) passN = n_points;

    if (passN < 256 || (n_points & 255) != 0) {
        int total = n_points * NLEVELS;
        hashgrid_fallback<<<(total + 255) / 256, 256, 0, stream>>>(x, tables, out, n_points, p);
        return;
    }

    uint32_t* btab = (uint32_t*)d_ws;
    float2* wsbuf = (float2*)((char*)d_ws + TAB_BYTES);

    convert_kernel<<<128 * NXCD, 256, 0, stream>>>(tables, btab, p);

    for (int p_lo = 0; p_lo < n_points; p_lo += passN) {
        int cnt = n_points - p_lo;
        if (cnt > passN) cnt = passN;
        int chunks = cnt / 256;
        gather_kernel<<<chunks * NXCD, 256, 0, stream>>>(x, btab, wsbuf, p_lo, cnt, p);
        transpose_kernel<<<chunks, 256, 0, stream>>>(wsbuf, (f4v*)out, p_lo, cnt);
    }
}